// Round 4
// baseline (348.057 us; speedup 1.0000x reference)
//
#include <hip/hip_runtime.h>

#define NSEG 511
#define NROWS 8            // rows 8..15 only
#define ROW0 8
#define K0 21              // first needed freq bin
#define KEND 500           // bins k with 20 < k < 500
#define NFREQ 479
#define ACC_STRIDE 512     // padded per-row accumulator stride
#define NBLOCKS (2 * NROWS * NSEG)

// XOR swizzle: permutes the i-digit (bits 2..4) by the j-digit (bits 5..7).
// Keeps bits 0..1 intact (float4 groups stay contiguous), bijective per 32-block.
__device__ __forceinline__ int sw(int i) { return i ^ (((i >> 5) & 7) << 2); }

// Position of bin k after in-place DIF with radices [8,8,8,4]:
// k = 512*k3 + 64*i + 8*j + p  ->  pos = k3 + 4*i + 32*j + 256*p
__device__ __forceinline__ int dr_pos(int k) {
    return ((k >> 9) & 3) + 4 * ((k >> 6) & 7) + 32 * ((k >> 3) & 7) + 256 * (k & 7);
}

__device__ __forceinline__ float2 cmul(float2 a, float2 b) {
    return make_float2(fmaf(a.x, b.x, -a.y * b.y), fmaf(a.x, b.y, a.y * b.x));
}
__device__ __forceinline__ float2 cadd(float2 a, float2 b) { return make_float2(a.x + b.x, a.y + b.y); }
__device__ __forceinline__ float2 csub(float2 a, float2 b) { return make_float2(a.x - b.x, a.y - b.y); }

// In-register 8-point DFT (DIF), fully scalarized (no local array -> no scratch).
__device__ __forceinline__ void dft8(float2& x0, float2& x1, float2& x2, float2& x3,
                                     float2& x4, float2& x5, float2& x6, float2& x7) {
    const float C45 = 0.70710678118654752440f;
    float2 t0 = cadd(x0, x4), u0 = csub(x0, x4);
    float2 t1 = cadd(x1, x5), u1 = csub(x1, x5);
    float2 t2 = cadd(x2, x6), u2 = csub(x2, x6);
    float2 t3 = cadd(x3, x7), u3 = csub(x3, x7);
    float2 s0 = cadd(t0, t2), d0 = csub(t0, t2);
    float2 s1 = cadd(t1, t3), d1 = csub(t1, t3);
    float2 v1 = make_float2(C45 * (u1.x + u1.y), C45 * (u1.y - u1.x));
    float2 v2 = make_float2(u2.y, -u2.x);
    float2 v3 = make_float2(C45 * (u3.y - u3.x), -C45 * (u3.x + u3.y));
    float2 s2 = cadd(u0, v2), d2 = csub(u0, v2);
    float2 s3 = cadd(v1, v3), d3 = csub(v1, v3);
    float2 mid1 = make_float2(d1.y, -d1.x);   // -i * d1
    float2 mid3 = make_float2(d3.y, -d3.x);   // -i * d3
    x0 = cadd(s0, s1); x4 = csub(s0, s1);
    x2 = cadd(d0, mid1); x6 = csub(d0, mid1);
    x1 = cadd(s2, s3); x5 = csub(s2, s3);
    x3 = cadd(d2, mid3); x7 = csub(d2, mid3);
}

// y[p] *= W^p with W = e^{i*ang}; 1 sincos + 6 cmuls. Scalarized.
__device__ __forceinline__ void twiddle8(float2& x1, float2& x2, float2& x3, float2& x4,
                                         float2& x5, float2& x6, float2& x7, float ang) {
    float s, c;
    __sincosf(ang, &s, &c);
    float2 w1 = make_float2(c, s);
    float2 w2 = cmul(w1, w1);
    float2 w3 = cmul(w2, w1);
    float2 w4 = cmul(w2, w2);
    float2 w5 = cmul(w4, w1);
    float2 w6 = cmul(w3, w3);
    float2 w7 = cmul(w4, w3);
    x1 = cmul(x1, w1); x2 = cmul(x2, w2); x3 = cmul(x3, w3);
    x4 = cmul(x4, w4); x5 = cmul(x5, w5); x6 = cmul(x6, w6);
    x7 = cmul(x7, w7);
}

// One block = one (signal, row, segment). Windowed 4096-pt real FFT via
// register-resident 2048-pt complex FFT, radices [8,8,8,4], 3 LDS exchanges.
// Last block (atomic ticket) performs the final ratio-reduction.
__global__ __launch_bounds__(256)
void psd_kernel(const float* __restrict__ pred,
                const float* __restrict__ target,
                float* __restrict__ acc, int* __restrict__ counter,
                float* __restrict__ out) {
    __shared__ float2 buf[2048];   // 16 KiB
    __shared__ int is_last;

    const int bid = blockIdx.x;
    const int seg = bid % NSEG;
    const int row = (bid / NSEG) % NROWS + ROW0;
    const int sig = bid / (NSEG * NROWS);   // 0 = res (target-pred), 1 = target
    const int tid = threadIdx.x;

    const float2* t2p = (const float2*)target;
    const float2* p2p = (const float2*)pred;

    // ---- load + window directly into named registers.
    // Complex point m = (real[2m], real[2m+1]); m = tid + 256*r.
    // Real sample 2m is at batch row 2*seg + (m>>9), float2 offset row*512 + (m&511).
    // Window: w[2m] = 1 - cos(2*pi*m/2048); w[2m+1] = 1 - cos(2*pi*m/2048 + pi/2048).
    const float WA = 3.06796157577128245e-3f;      // 2*pi/2048
    const float CD = 0.99999882344642529f;         // cos(pi/2048)
    const float SD = 1.53398018628476550e-3f;      // sin(pi/2048)
    const int base2 = 2 * seg * 8192 + row * 512 + tid;
    float2 x0, x1, x2, x3, x4, x5, x6, x7;
#define LOADW(R, X)                                                          \
    {                                                                        \
        int idx2 = base2 + ((R) >> 1) * 8192 + ((R) & 1) * 256;              \
        float2 v = t2p[idx2];                                                \
        if (sig == 0) { float2 p = p2p[idx2]; v.x -= p.x; v.y -= p.y; }      \
        float sa, ca;                                                        \
        __sincosf((float)(tid + 256 * (R)) * WA, &sa, &ca);                  \
        X = make_float2(v.x * (1.0f - ca),                                   \
                        v.y * (1.0f - (ca * CD - sa * SD)));                 \
    }
    LOADW(0, x0) LOADW(1, x1) LOADW(2, x2) LOADW(3, x3)
    LOADW(4, x4) LOADW(5, x5) LOADW(6, x6) LOADW(7, x7)
#undef LOADW

    // ---- stage A: radix-8 over stride 256 (q = tid), twiddle W2048^{q*p}
    dft8(x0, x1, x2, x3, x4, x5, x6, x7);
    twiddle8(x1, x2, x3, x4, x5, x6, x7, (float)tid * -3.06796157577128245e-3f);
    buf[sw(tid)]        = x0;
    buf[sw(tid + 256)]  = x1;
    buf[sw(tid + 512)]  = x2;
    buf[sw(tid + 768)]  = x3;
    buf[sw(tid + 1024)] = x4;
    buf[sw(tid + 1280)] = x5;
    buf[sw(tid + 1536)] = x6;
    buf[sw(tid + 1792)] = x7;
    __syncthreads();

    // ---- stage B: radix-8 over stride 32 within each 256-subFFT
    {
        const int pb = tid >> 5, q0 = tid & 31;
        const int baseB = q0 + 256 * pb;
        x0 = buf[sw(baseB)];
        x1 = buf[sw(baseB + 32)];
        x2 = buf[sw(baseB + 64)];
        x3 = buf[sw(baseB + 96)];
        x4 = buf[sw(baseB + 128)];
        x5 = buf[sw(baseB + 160)];
        x6 = buf[sw(baseB + 192)];
        x7 = buf[sw(baseB + 224)];
        dft8(x0, x1, x2, x3, x4, x5, x6, x7);
        twiddle8(x1, x2, x3, x4, x5, x6, x7, (float)q0 * -2.45436926061702596e-2f);
        __syncthreads();
        buf[sw(baseB)]       = x0;
        buf[sw(baseB + 32)]  = x1;
        buf[sw(baseB + 64)]  = x2;
        buf[sw(baseB + 96)]  = x3;
        buf[sw(baseB + 128)] = x4;
        buf[sw(baseB + 160)] = x5;
        buf[sw(baseB + 192)] = x6;
        buf[sw(baseB + 224)] = x7;
    }
    __syncthreads();

    // ---- stage C: radix-8 over stride 4 within each 32-subFFT
    {
        const int pb2 = tid >> 5, j2 = (tid >> 2) & 7, mq = tid & 3;
        const int baseC = mq + 32 * j2 + 256 * pb2;
        x0 = buf[sw(baseC)];
        x1 = buf[sw(baseC + 4)];
        x2 = buf[sw(baseC + 8)];
        x3 = buf[sw(baseC + 12)];
        x4 = buf[sw(baseC + 16)];
        x5 = buf[sw(baseC + 20)];
        x6 = buf[sw(baseC + 24)];
        x7 = buf[sw(baseC + 28)];
        dft8(x0, x1, x2, x3, x4, x5, x6, x7);
        twiddle8(x1, x2, x3, x4, x5, x6, x7, (float)mq * -1.96349540849362077e-1f);
        __syncthreads();
        buf[sw(baseC)]      = x0;
        buf[sw(baseC + 4)]  = x1;
        buf[sw(baseC + 8)]  = x2;
        buf[sw(baseC + 12)] = x3;
        buf[sw(baseC + 16)] = x4;
        buf[sw(baseC + 20)] = x5;
        buf[sw(baseC + 24)] = x6;
        buf[sw(baseC + 28)] = x7;
    }
    __syncthreads();

    // ---- stage D: 512 length-4 DFTs over contiguous quads (twiddle-free),
    // each thread does 2, via float4 pairs (swizzle keeps quads contiguous).
    float4* b4 = (float4*)buf;
#define STAGE_D(G)                                                           \
    {                                                                        \
        int pbase = sw(4 * (tid + 256 * (G)));                               \
        float4 lo = b4[(pbase >> 1)];                                        \
        float4 hi = b4[(pbase >> 1) + 1];                                    \
        float2 a0 = make_float2(lo.x, lo.y), a1 = make_float2(lo.z, lo.w);   \
        float2 a2 = make_float2(hi.x, hi.y), a3 = make_float2(hi.z, hi.w);   \
        float2 S0 = cadd(a0, a2), D0 = csub(a0, a2);                         \
        float2 S1 = cadd(a1, a3), D1 = csub(a1, a3);                         \
        float2 mi = make_float2(D1.y, -D1.x);                                \
        float2 X0 = cadd(S0, S1), X2 = csub(S0, S1);                         \
        float2 X1 = cadd(D0, mi), X3 = csub(D0, mi);                         \
        b4[(pbase >> 1)]     = make_float4(X0.x, X0.y, X1.x, X1.y);          \
        b4[(pbase >> 1) + 1] = make_float4(X2.x, X2.y, X3.x, X3.y);          \
    }
    STAGE_D(0) STAGE_D(1)
#undef STAGE_D
    __syncthreads();

    // ---- untangle real FFT + power + accumulate (bins 21..499)
#define UNTANGLE(RR)                                                         \
    {                                                                        \
        int k = K0 + tid + 256 * (RR);                                       \
        if (k < KEND) {                                                      \
            float2 zk = buf[sw(dr_pos(k))];                                  \
            float2 zn = buf[sw(dr_pos(2048 - k))];                           \
            float Ex = 0.5f * (zk.x + zn.x);                                 \
            float Ey = 0.5f * (zk.y - zn.y);                                 \
            float Ox = 0.5f * (zk.y + zn.y);                                 \
            float Oy = -0.5f * (zk.x - zn.x);                                \
            float sn, cs;                                                    \
            __sincosf(-1.53398078788564123e-3f * (float)k, &sn, &cs);        \
            float xr = Ex + Ox * cs - Oy * sn;                               \
            float xi = Ey + Ox * sn + Oy * cs;                               \
            float pw = xr * xr + xi * xi;                                    \
            atomicAdd(&acc[(sig * NROWS + (row - ROW0)) * ACC_STRIDE + (k - K0)], pw); \
        }                                                                    \
    }
    UNTANGLE(0) UNTANGLE(1)
#undef UNTANGLE

    // ---- last block reduces: out = sum(P_res/P_tgt) / 240
    // (dfreq=1, scale=480, mean(last 8)*16 => 2/480 = 1/240; /T cancels in ratio)
    __syncthreads();
    if (tid == 0) {
        __threadfence();
        int old = atomicAdd(counter, 1);
        is_last = (old == NBLOCKS - 1) ? 1 : 0;
    }
    __syncthreads();
    if (is_last) {
        float sum = 0.0f;
        for (int n = tid; n < NROWS * NFREQ; n += 256) {
            int r = n / NFREQ, k = n % NFREQ;
            float num = __hip_atomic_load(&acc[r * ACC_STRIDE + k],
                                          __ATOMIC_RELAXED, __HIP_MEMORY_SCOPE_AGENT);
            float den = __hip_atomic_load(&acc[(NROWS + r) * ACC_STRIDE + k],
                                          __ATOMIC_RELAXED, __HIP_MEMORY_SCOPE_AGENT);
            sum += num / den;
        }
        float* shf = (float*)buf;
        shf[tid] = sum;
        __syncthreads();
        for (int s2 = 128; s2 > 0; s2 >>= 1) {
            if (tid < s2) shf[tid] += shf[tid + s2];
            __syncthreads();
        }
        if (tid == 0) out[0] = shf[0] * (1.0f / 240.0f);
    }
}

extern "C" void kernel_launch(void* const* d_in, const int* in_sizes, int n_in,
                              void* d_out, int out_size, void* d_ws, size_t ws_size,
                              hipStream_t stream) {
    const float* pred = (const float*)d_in[0];
    const float* target = (const float*)d_in[1];
    float* acc = (float*)d_ws;                         // [2][NROWS][ACC_STRIDE]
    int* counter = (int*)(acc + 2 * NROWS * ACC_STRIDE);

    hipMemsetAsync(d_ws, 0, (2 * NROWS * ACC_STRIDE + 1) * sizeof(float), stream);
    psd_kernel<<<NBLOCKS, 256, 0, stream>>>(pred, target, acc, counter, (float*)d_out);
}

// Round 5
// 190.340 us; speedup vs baseline: 1.8286x; 1.8286x over previous
//
#include <hip/hip_runtime.h>

#define NSEG 511
#define NROWS 8            // rows 8..15 only
#define ROW0 8
#define K0 21              // first needed freq bin
#define KEND 500           // bins k with 20 < k < 500
#define NFREQ 479
#define ACC_STRIDE 512     // padded per-row accumulator stride
#define ACC_ELEMS (2 * NROWS * ACC_STRIDE)   // one replica
#define NREP 8             // accumulator replicas (cuts atomic contention 8x)
#define NBLOCKS (2 * NROWS * NSEG)

// XOR swizzle: permutes the i-digit (bits 2..4) by the j-digit (bits 5..7).
// Keeps bits 0..1 intact (float4 groups stay contiguous), bijective per 32-block.
__device__ __forceinline__ int sw(int i) { return i ^ (((i >> 5) & 7) << 2); }

// Position of bin k after in-place DIF with radices [8,8,8,4]:
// k = 512*k3 + 64*i + 8*j + p  ->  pos = k3 + 4*i + 32*j + 256*p
__device__ __forceinline__ int dr_pos(int k) {
    return ((k >> 9) & 3) + 4 * ((k >> 6) & 7) + 32 * ((k >> 3) & 7) + 256 * (k & 7);
}

__device__ __forceinline__ float2 cmul(float2 a, float2 b) {
    return make_float2(fmaf(a.x, b.x, -a.y * b.y), fmaf(a.x, b.y, a.y * b.x));
}
__device__ __forceinline__ float2 cadd(float2 a, float2 b) { return make_float2(a.x + b.x, a.y + b.y); }
__device__ __forceinline__ float2 csub(float2 a, float2 b) { return make_float2(a.x - b.x, a.y - b.y); }

// In-register 8-point DFT (DIF).
__device__ __forceinline__ void dft8(float2& x0, float2& x1, float2& x2, float2& x3,
                                     float2& x4, float2& x5, float2& x6, float2& x7) {
    const float C45 = 0.70710678118654752440f;
    float2 t0 = cadd(x0, x4), u0 = csub(x0, x4);
    float2 t1 = cadd(x1, x5), u1 = csub(x1, x5);
    float2 t2 = cadd(x2, x6), u2 = csub(x2, x6);
    float2 t3 = cadd(x3, x7), u3 = csub(x3, x7);
    float2 s0 = cadd(t0, t2), d0 = csub(t0, t2);
    float2 s1 = cadd(t1, t3), d1 = csub(t1, t3);
    float2 v1 = make_float2(C45 * (u1.x + u1.y), C45 * (u1.y - u1.x));
    float2 v2 = make_float2(u2.y, -u2.x);
    float2 v3 = make_float2(C45 * (u3.y - u3.x), -C45 * (u3.x + u3.y));
    float2 s2 = cadd(u0, v2), d2 = csub(u0, v2);
    float2 s3 = cadd(v1, v3), d3 = csub(v1, v3);
    float2 mid1 = make_float2(d1.y, -d1.x);   // -i * d1
    float2 mid3 = make_float2(d3.y, -d3.x);   // -i * d3
    x0 = cadd(s0, s1); x4 = csub(s0, s1);
    x2 = cadd(d0, mid1); x6 = csub(d0, mid1);
    x1 = cadd(s2, s3); x5 = csub(s2, s3);
    x3 = cadd(d2, mid3); x7 = csub(d2, mid3);
}

// x[p] *= W^p with W = e^{i*ang}; 1 sincos + 6 cmuls to build powers.
__device__ __forceinline__ void twiddle8(float2& x1, float2& x2, float2& x3, float2& x4,
                                         float2& x5, float2& x6, float2& x7, float ang) {
    float s, c;
    __sincosf(ang, &s, &c);
    float2 w1 = make_float2(c, s);
    float2 w2 = cmul(w1, w1);
    float2 w3 = cmul(w2, w1);
    float2 w4 = cmul(w2, w2);
    float2 w5 = cmul(w4, w1);
    float2 w6 = cmul(w3, w3);
    float2 w7 = cmul(w4, w3);
    x1 = cmul(x1, w1); x2 = cmul(x2, w2); x3 = cmul(x3, w3);
    x4 = cmul(x4, w4); x5 = cmul(x5, w5); x6 = cmul(x6, w6);
    x7 = cmul(x7, w7);
}

// One block = one (signal, row, segment). Windowed 4096-pt real FFT via
// register-resident 2048-pt complex FFT, radices [8,8,8,4], 3 LDS exchanges.
// Fire-and-forget atomic accumulation into replica (bid & 7); NO tail sync.
__global__ __launch_bounds__(256)
void psd_kernel(const float* __restrict__ pred,
                const float* __restrict__ target,
                float* __restrict__ acc) {
    __shared__ float2 buf[2048];   // 16 KiB

    const int bid = blockIdx.x;
    const int seg = bid % NSEG;
    const int row = (bid / NSEG) % NROWS + ROW0;
    const int sig = bid / (NSEG * NROWS);   // 0 = res (target-pred), 1 = target
    const int tid = threadIdx.x;
    float* accR = acc + (bid & (NREP - 1)) * ACC_ELEMS;

    const float2* t2p = (const float2*)target;
    const float2* p2p = (const float2*)pred;

    // ---- load + window into named registers.
    // Complex point m = (real[2m], real[2m+1]); m = tid + 256*r.
    // Real sample 2m is at batch row 2*seg + (m>>9), float2 offset row*512 + (m&511).
    // w[2m] = 1 - cos(2*pi*m/2048); w[2m+1] = 1 - cos(2*pi*m/2048 + pi/2048).
    const float WA = 3.06796157577128245e-3f;      // 2*pi/2048
    const float CD = 0.99999882344642529f;         // cos(pi/2048)
    const float SD = 1.53398018628476550e-3f;      // sin(pi/2048)
    const int base2 = 2 * seg * 8192 + row * 512 + tid;
    float2 x0, x1, x2, x3, x4, x5, x6, x7;
#define LOADW(R, X)                                                          \
    {                                                                        \
        int idx2 = base2 + ((R) >> 1) * 8192 + ((R) & 1) * 256;              \
        float2 v = t2p[idx2];                                                \
        if (sig == 0) { float2 p = p2p[idx2]; v.x -= p.x; v.y -= p.y; }      \
        float sa, ca;                                                        \
        __sincosf((float)(tid + 256 * (R)) * WA, &sa, &ca);                  \
        X = make_float2(v.x * (1.0f - ca),                                   \
                        v.y * (1.0f - (ca * CD - sa * SD)));                 \
    }
    LOADW(0, x0) LOADW(1, x1) LOADW(2, x2) LOADW(3, x3)
    LOADW(4, x4) LOADW(5, x5) LOADW(6, x6) LOADW(7, x7)
#undef LOADW

    // ---- stage A: radix-8 over stride 256 (q = tid), twiddle W2048^{q*p}
    dft8(x0, x1, x2, x3, x4, x5, x6, x7);
    twiddle8(x1, x2, x3, x4, x5, x6, x7, (float)tid * -3.06796157577128245e-3f);
    buf[sw(tid)]        = x0;
    buf[sw(tid + 256)]  = x1;
    buf[sw(tid + 512)]  = x2;
    buf[sw(tid + 768)]  = x3;
    buf[sw(tid + 1024)] = x4;
    buf[sw(tid + 1280)] = x5;
    buf[sw(tid + 1536)] = x6;
    buf[sw(tid + 1792)] = x7;
    __syncthreads();

    // ---- stage B: radix-8 over stride 32 within each 256-subFFT.
    // Each thread reads & writes its own 8 slots -> no internal barrier.
    {
        const int pb = tid >> 5, q0 = tid & 31;
        const int baseB = q0 + 256 * pb;
        x0 = buf[sw(baseB)];
        x1 = buf[sw(baseB + 32)];
        x2 = buf[sw(baseB + 64)];
        x3 = buf[sw(baseB + 96)];
        x4 = buf[sw(baseB + 128)];
        x5 = buf[sw(baseB + 160)];
        x6 = buf[sw(baseB + 192)];
        x7 = buf[sw(baseB + 224)];
        dft8(x0, x1, x2, x3, x4, x5, x6, x7);
        twiddle8(x1, x2, x3, x4, x5, x6, x7, (float)q0 * -2.45436926061702596e-2f);
        buf[sw(baseB)]       = x0;
        buf[sw(baseB + 32)]  = x1;
        buf[sw(baseB + 64)]  = x2;
        buf[sw(baseB + 96)]  = x3;
        buf[sw(baseB + 128)] = x4;
        buf[sw(baseB + 160)] = x5;
        buf[sw(baseB + 192)] = x6;
        buf[sw(baseB + 224)] = x7;
    }
    __syncthreads();

    // ---- stage C: radix-8 over stride 4 within each 32-subFFT.
    {
        const int pb2 = tid >> 5, j2 = (tid >> 2) & 7, mq = tid & 3;
        const int baseC = mq + 32 * j2 + 256 * pb2;
        x0 = buf[sw(baseC)];
        x1 = buf[sw(baseC + 4)];
        x2 = buf[sw(baseC + 8)];
        x3 = buf[sw(baseC + 12)];
        x4 = buf[sw(baseC + 16)];
        x5 = buf[sw(baseC + 20)];
        x6 = buf[sw(baseC + 24)];
        x7 = buf[sw(baseC + 28)];
        dft8(x0, x1, x2, x3, x4, x5, x6, x7);
        twiddle8(x1, x2, x3, x4, x5, x6, x7, (float)mq * -1.96349540849362077e-1f);
        buf[sw(baseC)]      = x0;
        buf[sw(baseC + 4)]  = x1;
        buf[sw(baseC + 8)]  = x2;
        buf[sw(baseC + 12)] = x3;
        buf[sw(baseC + 16)] = x4;
        buf[sw(baseC + 20)] = x5;
        buf[sw(baseC + 24)] = x6;
        buf[sw(baseC + 28)] = x7;
    }
    __syncthreads();

    // ---- stage D: 512 length-4 DFTs over contiguous quads (twiddle-free),
    // each thread does 2, via float4 pairs (swizzle keeps quads contiguous).
    float4* b4 = (float4*)buf;
#define STAGE_D(G)                                                           \
    {                                                                        \
        int pbase = sw(4 * (tid + 256 * (G)));                               \
        float4 lo = b4[(pbase >> 1)];                                        \
        float4 hi = b4[(pbase >> 1) + 1];                                    \
        float2 a0 = make_float2(lo.x, lo.y), a1 = make_float2(lo.z, lo.w);   \
        float2 a2 = make_float2(hi.x, hi.y), a3 = make_float2(hi.z, hi.w);   \
        float2 S0 = cadd(a0, a2), D0 = csub(a0, a2);                         \
        float2 S1 = cadd(a1, a3), D1 = csub(a1, a3);                         \
        float2 mi = make_float2(D1.y, -D1.x);                                \
        float2 X0 = cadd(S0, S1), X2 = csub(S0, S1);                         \
        float2 X1 = cadd(D0, mi), X3 = csub(D0, mi);                         \
        b4[(pbase >> 1)]     = make_float4(X0.x, X0.y, X1.x, X1.y);          \
        b4[(pbase >> 1) + 1] = make_float4(X2.x, X2.y, X3.x, X3.y);          \
    }
    STAGE_D(0) STAGE_D(1)
#undef STAGE_D
    __syncthreads();

    // ---- untangle real FFT + power + accumulate (bins 21..499), fire-and-forget.
#define UNTANGLE(RR)                                                         \
    {                                                                        \
        int k = K0 + tid + 256 * (RR);                                       \
        if (k < KEND) {                                                      \
            float2 zk = buf[sw(dr_pos(k))];                                  \
            float2 zn = buf[sw(dr_pos(2048 - k))];                           \
            float Ex = 0.5f * (zk.x + zn.x);                                 \
            float Ey = 0.5f * (zk.y - zn.y);                                 \
            float Ox = 0.5f * (zk.y + zn.y);                                 \
            float Oy = -0.5f * (zk.x - zn.x);                                \
            float sn, cs;                                                    \
            __sincosf(-1.53398078788564123e-3f * (float)k, &sn, &cs);        \
            float xr = Ex + Ox * cs - Oy * sn;                               \
            float xi = Ey + Ox * sn + Oy * cs;                               \
            float pw = xr * xr + xi * xi;                                    \
            atomicAdd(&accR[(sig * NROWS + (row - ROW0)) * ACC_STRIDE + (k - K0)], pw); \
        }                                                                    \
    }
    UNTANGLE(0) UNTANGLE(1)
#undef UNTANGLE
}

// Single block: out = sum over (row,k) of P_res/P_tgt, / 240.
// (dfreq=1, scale=480, mean(last 8)*16 => 2/480 = 1/240; /T cancels in ratio)
__global__ __launch_bounds__(256)
void reduce_kernel(const float* __restrict__ acc, float* __restrict__ out) {
    __shared__ float sh[256];
    int tid = threadIdx.x;
    float sum = 0.0f;
    for (int n = tid; n < NROWS * NFREQ; n += 256) {
        int r = n / NFREQ, k = n % NFREQ;
        float num = 0.0f, den = 0.0f;
        #pragma unroll
        for (int rep = 0; rep < NREP; ++rep) {
            num += acc[rep * ACC_ELEMS + r * ACC_STRIDE + k];
            den += acc[rep * ACC_ELEMS + (NROWS + r) * ACC_STRIDE + k];
        }
        sum += num / den;
    }
    sh[tid] = sum;
    __syncthreads();
    for (int s = 128; s > 0; s >>= 1) {
        if (tid < s) sh[tid] += sh[tid + s];
        __syncthreads();
    }
    if (tid == 0) out[0] = sh[0] * (1.0f / 240.0f);
}

extern "C" void kernel_launch(void* const* d_in, const int* in_sizes, int n_in,
                              void* d_out, int out_size, void* d_ws, size_t ws_size,
                              hipStream_t stream) {
    const float* pred = (const float*)d_in[0];
    const float* target = (const float*)d_in[1];
    float* acc = (float*)d_ws;   // NREP replicas of [2][NROWS][ACC_STRIDE] = 256 KiB

    hipMemsetAsync(acc, 0, NREP * ACC_ELEMS * sizeof(float), stream);
    psd_kernel<<<NBLOCKS, 256, 0, stream>>>(pred, target, acc);
    reduce_kernel<<<1, 256, 0, stream>>>(acc, (float*)d_out);
}